// Round 7
// baseline (271.594 us; speedup 1.0000x reference)
//
// AttentionModel: fused QKV projection + causal softmax attention, MI355X/gfx950.
// Round 10: BK=128 -- halve the phase count. Calibrated model (R8 1-block/CU:
// 2.9us/phase; R9: 3.5us/phase at 2.5 blocks): each stage->sync->compute->sync
// K-step costs ~2 exposed memory round-trips REGARDLESS of per-phase work.
// So double per-phase work: BK 64->128, phases 8->4 (proj/scores), pv qt+1.
//  - Conflict-free BK=128 contract (derived, lane-checked): row = 16 slots x
//    8 halfs; PHYSICAL slot = LOGICAL ^ (row&7). gload_lds dest stays linear
//    (tid*16B), XOR applied on the global source slot; ds_read_b128 compute
//    reads slot (ks*4+fq)^(fr&7). Both staging writes and fragment reads land
//    on the 8-bank-cycle wave64 floor (= conflict-free). R5's BK=32 failure
//    was a broken swizzle (64B rows can't spread), not the phase-count idea.
//  - LDS 64 KB single-buffered (As+Bs) -> 2 blocks/CU; launch_bounds(256,2).
//  - proj A (fp32): 16 f32x4 reg-loads + cvt, written to swizzled slots; B via
//    gload_lds. A-loads issued before B so the cvt waits only on A.
//  - Epilogues / grids / softmax / V-direct-transpose: identical to R9 (best).
// ws layout (bytes): P 0..64M | Qb 64M | Kb 80M | Vt 112M | Wf16 128M

#include <hip/hip_runtime.h>
#include <stdint.h>
#include <stddef.h>
#include <math.h>

typedef _Float16 half8 __attribute__((ext_vector_type(8)));
typedef float f32x4 __attribute__((ext_vector_type(4)));

#define SCALE_QK 0.04419417382415922f  // 1/sqrt(512)

__device__ __forceinline__ void gload16(const void* g, void* lds) {
  __builtin_amdgcn_global_load_lds(
      (const __attribute__((address_space(1))) void*)g,
      (__attribute__((address_space(3))) void*)lds,
      16, 0, 0);
}

// K-loop: C[128x128] = A[128xK] * B^T (B stored [N][K]), f16 MFMA, BK=128.
// SINGLE-buffered: stage -> sync -> compute(4 ks-slices) -> sync.
// LDS contract: row r = 16 slots of 8 halfs; physical slot p holds logical
// p^(r&7). Stage: linear dest (tid*8 halfs), source slot sg^(srow&7).
// Read: logical (ks*4+fq) at physical (ks*4+fq)^(fr&7).
template<bool A_F32>
__device__ __forceinline__ void run_kloop128(const void* Arow0, const _Float16* Brow0,
                                             int lda, int ldb, int kIters,
                                             _Float16* As, _Float16* Bs,
                                             f32x4 (&acc)[4][4])
{
  const int tid  = threadIdx.x;
  const int lane = tid & 63;
  const int w    = tid >> 6;
  const int wm   = w >> 1, wn = w & 1;
  const int srow = tid >> 4;          // staging row within 16-row chunk (0..15)
  const int sg   = tid & 15;          // staging slot (16 slots/row)
  const int swz  = sg ^ (srow & 7);   // swizzled slot (source side / fp32 dest)
  const int fr   = lane & 15;         // fragment m/n within 16
  const int fq   = lane >> 4;         // k-quad within 32-k slice
  const int fx   = lane & 7;          // read-side swizzle = fr & 7

  for (int it = 0; it < kIters; ++it) {
    const int k0 = it * 128;
    if constexpr (A_F32) {
      const float* A = (const float*)Arow0;
      f32x4 preF[16];
      #pragma unroll
      for (int i = 0; i < 8; ++i) {   // A first: cvt waits only on these
        const float* src = A + (size_t)(i*16 + srow) * lda + (k0 + sg*8);
        preF[2*i]   = *(const f32x4*)src;
        preF[2*i+1] = *(const f32x4*)(src + 4);
      }
      #pragma unroll
      for (int i = 0; i < 8; ++i)
        gload16(Brow0 + (size_t)(i*16 + srow) * ldb + (k0 + swz*8), Bs + i*2048 + tid*8);
      #pragma unroll
      for (int i = 0; i < 8; ++i) {   // cvt + swizzled LDS write
        f32x4 x = preF[2*i], y = preF[2*i+1];
        half8 h;
        h[0]=(_Float16)x[0]; h[1]=(_Float16)x[1]; h[2]=(_Float16)x[2]; h[3]=(_Float16)x[3];
        h[4]=(_Float16)y[0]; h[5]=(_Float16)y[1]; h[6]=(_Float16)y[2]; h[7]=(_Float16)y[3];
        *(half8*)(As + (i*16 + srow)*128 + swz*8) = h;
      }
    } else {
      const _Float16* A = (const _Float16*)Arow0;
      #pragma unroll
      for (int i = 0; i < 8; ++i)
        gload16(A + (size_t)(i*16 + srow) * lda + (k0 + swz*8), As + i*2048 + tid*8);
      #pragma unroll
      for (int i = 0; i < 8; ++i)
        gload16(Brow0 + (size_t)(i*16 + srow) * ldb + (k0 + swz*8), Bs + i*2048 + tid*8);
    }
    __syncthreads();   // drains vmcnt (gload_lds) + lgkm (A writes): tile ready

    #pragma unroll
    for (int ks = 0; ks < 4; ++ks) {
      half8 av[4], bv[4];
      const int slot = (ks*4 + fq) ^ fx;
      #pragma unroll
      for (int i = 0; i < 4; ++i) {
        av[i] = *(const half8*)(As + (wm*64 + i*16 + fr)*128 + slot*8);
        bv[i] = *(const half8*)(Bs + (wn*64 + i*16 + fr)*128 + slot*8);
      }
      #pragma unroll
      for (int i = 0; i < 4; ++i) {
        #pragma unroll
        for (int j = 0; j < 4; ++j)
          acc[i][j] = __builtin_amdgcn_mfma_f32_16x16x32_f16(av[i], bv[j], acc[i][j], 0, 0, 0);
      }
    }
    __syncthreads();   // all reads done before next iteration's overwrite
  }
}

// ---- weights fp32 -> f16 (3 x 512x512 concatenated) ----
__global__ __launch_bounds__(256) void k_cvtw(const float* __restrict__ Wq,
                                              const float* __restrict__ Wk,
                                              const float* __restrict__ Wv,
                                              _Float16* __restrict__ Wb)
{
  const int t = blockIdx.x * 256 + threadIdx.x;
  const int base = t * 8;
  const int z = base >> 18;
  const int off = base & 262143;
  const float* src = (z == 0) ? Wq : ((z == 1) ? Wk : Wv);
  f32x4 a = *(const f32x4*)(src + off);
  f32x4 b = *(const f32x4*)(src + off + 4);
  half8 h;
  h[0]=(_Float16)a[0]; h[1]=(_Float16)a[1]; h[2]=(_Float16)a[2]; h[3]=(_Float16)a[3];
  h[4]=(_Float16)b[0]; h[5]=(_Float16)b[1]; h[6]=(_Float16)b[2]; h[7]=(_Float16)b[3];
  *(half8*)(Wb + base) = h;
}

// ---- projections: X[16384x512](fp32) @ W^T + bias -> f16; V direct-transposed ----
// 1D grid 1536: xcd = bid%8; panel p = xcd*48 + i/4; nt = i%4; z = p/128, mt = p%128.
// LDS: union of {As 32KB + Bs 32KB} and the V-transpose tile [128][132].
__global__ __launch_bounds__(256, 2) void k_proj(const float* __restrict__ q,
                                                 const float* __restrict__ k,
                                                 const float* __restrict__ v,
                                                 const _Float16* __restrict__ Wb,
                                                 const float* __restrict__ bq,
                                                 const float* __restrict__ bk,
                                                 const float* __restrict__ bv,
                                                 _Float16* __restrict__ Qb,
                                                 _Float16* __restrict__ Kb,
                                                 _Float16* __restrict__ Vt)
{
  __shared__ __align__(16) _Float16 LDSbuf[2*128*128];   // 64 KB union
  _Float16* As = LDSbuf;
  _Float16* Bs = LDSbuf + 16384;

  const int bid = blockIdx.x;
  const int xcd = bid & 7, i = bid >> 3;
  const int p = xcd * 48 + (i >> 2);
  const int nt = i & 3;
  const int z = p >> 7, mt = p & 127;

  const float* A     = (z == 0) ? q  : (z == 1) ? k  : v;
  const float* bia   = (z == 0) ? bq : (z == 1) ? bk : bv;
  const _Float16* B  = Wb + (size_t)z * 512 * 512;

  f32x4 acc[4][4] = {};
  run_kloop128<true>(A + (size_t)mt*128*512, B + (size_t)nt*128*512, 512, 512, 4,
                     As, Bs, acc);

  const int tid = threadIdx.x;
  const int lane = tid & 63, w = tid >> 6;
  const int wm = w >> 1, wn = w & 1;
  const int fr = lane & 15, fq = lane >> 4;   // C/D: col=lane&15, row=(lane>>4)*4+reg

  if (z < 2) {
    _Float16* C = (z == 0) ? Qb : Kb;
    #pragma unroll
    for (int j = 0; j < 4; ++j) {
      const int col = nt*128 + wn*64 + j*16 + fr;
      const float bval = bia[col];
      #pragma unroll
      for (int i2 = 0; i2 < 4; ++i2) {
        const int row = mt*128 + wm*64 + i2*16 + fq*4;
        #pragma unroll
        for (int r = 0; r < 4; ++r)
          C[(size_t)(row + r) * 512 + col] = (_Float16)(acc[i2][j][r] + bval);
      }
    }
  } else {
    // V: stage transposed tile in LDS [col 128][row 128 + pad 4], write Vt coalesced.
    _Float16* sm = LDSbuf;   // kloop ended with syncthreads: LDS free
    #pragma unroll
    for (int j = 0; j < 4; ++j) {
      const int colloc = wn*64 + j*16 + fr;
      const float bval = bia[nt*128 + colloc];
      #pragma unroll
      for (int i2 = 0; i2 < 4; ++i2) {
        const int rowloc = wm*64 + i2*16 + fq*4;
        #pragma unroll
        for (int r = 0; r < 4; ++r)
          sm[colloc*132 + rowloc + r] = (_Float16)(acc[i2][j][r] + bval);
      }
    }
    __syncthreads();
    const int bb = mt >> 4, s0 = (mt & 15) * 128;
    #pragma unroll
    for (int q8 = 0; q8 < 8; ++q8) {
      const int dloc = q8*16 + (tid >> 4);
      const int ch   = tid & 15;
      half8 o = *(const half8*)&sm[dloc*132 + ch*8];
      *(half8*)(Vt + ((size_t)bb*512 + nt*128 + dloc)*2048 + s0 + ch*8) = o;
    }
  }
}

// ---- scores: S = Q K^T * scale ----
// 1D grid 1088: b = bid%8 (-> XCD b); t = bid/8 triangular-decoded to (qt,kt),
// kt<=qt. Per-batch Q+K (4MB) is L2-resident on its XCD.
__global__ __launch_bounds__(256, 2) void k_scores(const _Float16* __restrict__ Qb,
                                                   const _Float16* __restrict__ Kb,
                                                   _Float16* __restrict__ P)
{
  __shared__ __align__(16) _Float16 As[128*128], Bs[128*128];   // 64 KB
  const int bid = blockIdx.x;
  const int b = bid & 7;
  const int t = bid >> 3;
  int qt = (int)((sqrtf(8.0f * (float)t + 1.0f) - 1.0f) * 0.5f);
  int base = (qt * (qt + 1)) >> 1;
  if (t < base)                { --qt; base = (qt * (qt + 1)) >> 1; }
  else if (t >= base + qt + 1) { ++qt; base = (qt * (qt + 1)) >> 1; }
  const int kt = t - base;

  f32x4 acc[4][4] = {};
  run_kloop128<false>(Qb + ((size_t)b*2048 + qt*128)*512,
                      Kb + ((size_t)b*2048 + kt*128)*512,
                      512, 512, 4, As, Bs, acc);
  const int lane = threadIdx.x & 63, w = threadIdx.x >> 6;
  const int wm = w >> 1, wn = w & 1;
  const int fr = lane & 15, fq = lane >> 4;
  #pragma unroll
  for (int i = 0; i < 4; ++i) {
    const int row = qt*128 + wm*64 + i*16 + fq*4;
    #pragma unroll
    for (int j = 0; j < 4; ++j) {
      const int col = kt*128 + wn*64 + j*16 + fr;
      #pragma unroll
      for (int r = 0; r < 4; ++r)
        P[((size_t)b*2048 + row + r) * 2048 + col] = (_Float16)(acc[i][j][r] * SCALE_QK);
    }
  }
}

// ---- in-place causal row softmax; one wave per row; row cached in regs ----
__global__ __launch_bounds__(256) void k_softmax(_Float16* __restrict__ P)
{
  const int lane = threadIdx.x & 63;
  const int row  = blockIdx.x * 4 + (threadIdx.x >> 6);  // 0..16383 (= b*2048+q)
  const int qIdx = row & 2047;
  _Float16* p = P + (size_t)row * 2048;
  const int L    = qIdx + 1;
  const int Lpad = ((qIdx >> 7) + 1) * 128;     // PV kernel reads up to here

  half8 xb[4];
  float m = -1e30f, s = 0.f;
  #pragma unroll
  for (int c = 0; c < 4; ++c) {
    const int i0 = lane * 8 + c * 512;
    if (i0 < Lpad) {
      half8 x = *(const half8*)(p + i0);
      xb[c] = x;
      float xv[8];
      #pragma unroll
      for (int j = 0; j < 8; ++j) xv[j] = (i0 + j < L) ? (float)x[j] : -1e30f;
      float cm = xv[0];
      #pragma unroll
      for (int j = 1; j < 8; ++j) cm = fmaxf(cm, xv[j]);
      const float mn = fmaxf(m, cm);
      float cs = 0.f;
      #pragma unroll
      for (int j = 0; j < 8; ++j) cs += __expf(xv[j] - mn);
      s = s * __expf(m - mn) + cs;
      m = mn;
    }
  }
  #pragma unroll
  for (int d = 1; d < 64; d <<= 1) {
    const float mo = __shfl_xor(m, d, 64);
    const float so = __shfl_xor(s, d, 64);
    const float mn = fmaxf(m, mo);
    s = s * __expf(m - mn) + so * __expf(mo - mn);
    m = mn;
  }
  const float inv = 1.0f / s;

  #pragma unroll
  for (int c = 0; c < 4; ++c) {
    const int i0 = lane * 8 + c * 512;
    if (i0 < Lpad) {
      half8 x = xb[c];
      half8 o;
      #pragma unroll
      for (int j = 0; j < 8; ++j)
        o[j] = (i0 + j < L) ? (_Float16)(__expf((float)x[j] - m) * inv) : (_Float16)0.f;
      *(half8*)(p + i0) = o;
    }
  }
}

// ---- out = P @ V  (B-operand = Vt[d][s]), causal K-extent ----
// 1D grid 512: b = bid%8 (-> XCD b); r = bid/8 in [0,64): qi=r/4 interleaved
// long/short (phase-balanced block pairs per CU), dt=r%4 (P rows L2-hot).
__global__ __launch_bounds__(256, 2) void k_pv(const _Float16* __restrict__ P,
                                               const _Float16* __restrict__ Vt,
                                               float* __restrict__ Out)
{
  __shared__ __align__(16) _Float16 As[128*128], Bs[128*128];   // 64 KB
  const int bid = blockIdx.x;
  const int b = bid & 7;
  const int r0 = bid >> 3;
  const int qi = r0 >> 2, dt = r0 & 3;
  const int qt = (qi & 1) ? (15 - (qi >> 1)) : (qi >> 1);

  f32x4 acc[4][4] = {};
  run_kloop128<false>(P  + ((size_t)b*2048 + qt*128)*2048,
                      Vt + ((size_t)b*512  + dt*128)*2048,
                      2048, 2048, qt + 1, As, Bs, acc);
  const int lane = threadIdx.x & 63, w = threadIdx.x >> 6;
  const int wm = w >> 1, wn = w & 1;
  const int fr = lane & 15, fq = lane >> 4;
  #pragma unroll
  for (int i = 0; i < 4; ++i) {
    const int row = qt*128 + wm*64 + i*16 + fq*4;
    #pragma unroll
    for (int j = 0; j < 4; ++j) {
      const int col = dt*128 + wn*64 + j*16 + fr;
      #pragma unroll
      for (int r = 0; r < 4; ++r)
        Out[((size_t)b*2048 + row + r) * 512 + col] = acc[i][j][r];
    }
  }
}

extern "C" void kernel_launch(void* const* d_in, const int* in_sizes, int n_in,
                              void* d_out, int out_size, void* d_ws, size_t ws_size,
                              hipStream_t stream) {
  (void)in_sizes; (void)n_in; (void)out_size;
  const float* q  = (const float*)d_in[0];
  const float* k  = (const float*)d_in[1];
  const float* v  = (const float*)d_in[2];
  // d_in[3] = causal mask: always tril per setup; implemented structurally.
  const float* Wq = (const float*)d_in[4];
  const float* bq = (const float*)d_in[5];
  const float* Wk = (const float*)d_in[6];
  const float* bk = (const float*)d_in[7];
  const float* Wv = (const float*)d_in[8];
  const float* bv = (const float*)d_in[9];

  const size_t OFF_P  = 0;
  const size_t OFF_Q  = (size_t)64 << 20;
  const size_t OFF_K  = (size_t)80 << 20;
  const size_t OFF_VT = (size_t)112 << 20;
  const size_t OFF_W  = (size_t)128 << 20;
  const size_t NEEDED = OFF_W + (size_t)3 * 512 * 512 * sizeof(_Float16);
  if (ws_size < NEEDED) return;  // diagnostic: poison-level absmax => ws too small

  char* ws = (char*)d_ws;
  _Float16* P  = (_Float16*)(ws + OFF_P);
  _Float16* Qb = (_Float16*)(ws + OFF_Q);
  _Float16* Kb = (_Float16*)(ws + OFF_K);
  _Float16* Vt = (_Float16*)(ws + OFF_VT);
  _Float16* Wb = (_Float16*)(ws + OFF_W);
  float* Out = (float*)d_out;

  k_cvtw   <<<dim3(384),  dim3(256), 0, stream>>>(Wq, Wk, Wv, Wb);
  k_proj   <<<dim3(1536), dim3(256), 0, stream>>>(q, k, v, Wb, bq, bk, bv, Qb, Kb, Vt);
  k_scores <<<dim3(1088), dim3(256), 0, stream>>>(Qb, Kb, P);
  k_softmax<<<dim3(4096), dim3(256), 0, stream>>>(P);
  k_pv     <<<dim3(512),  dim3(256), 0, stream>>>(P, Vt, Out);
}

// Round 8
// 270.502 us; speedup vs baseline: 1.0040x; 1.0040x over previous
//
// AttentionModel: fused QKV projection + causal softmax attention, MI355X/gfx950.
// Round 11: reduce STAGED BYTES (the real bound). Calibration across R8-R10:
// staging saturates ~33 GB/s/CU (~8.5 TB/s fabric), phase cost scales with
// bytes, invariant to sync scheme (R9 proj: 590MB staged / 8.5 = 69us = meas).
// => cut operand re-staging with 128x256 blocks:
//  - proj nt-PAIRS: A-panel re-read 4x->2x (590->393MB, predict ~48us).
//    acc[4][8], B-tile 256x64 f16 (32KB) + As 16KB; V-epilogue widened to
//    [256][132] union (66KB LDS, 2 blocks/CU).
//  - scores kt-PAIRS: 576 blocks heavy-first, wave-col half == kt sub-tile
//    (R8's verified epilogue), diagonal-masked, overshoot sub-tile unstored.
//  - pv / softmax / cvtw: byte-identical to R9 (best; pv 2+/CU needed for
//    overlap -- R8 proved 1 block/CU exposes serial phase latency).
//  - BK=64 + proven zero-conflict swizzle everywhere (R10's BK=128 reverted).
// ws layout (bytes): P 0..64M | Qb 64M | Kb 80M | Vt 112M | Wf16 128M

#include <hip/hip_runtime.h>
#include <stdint.h>
#include <stddef.h>
#include <math.h>

typedef _Float16 half8 __attribute__((ext_vector_type(8)));
typedef float f32x4 __attribute__((ext_vector_type(4)));

#define SCALE_QK 0.04419417382415922f  // 1/sqrt(512)

__device__ __forceinline__ void gload16(const void* g, void* lds) {
  __builtin_amdgcn_global_load_lds(
      (const __attribute__((address_space(1))) void*)g,
      (__attribute__((address_space(3))) void*)lds,
      16, 0, 0);
}

// ---- wide K-loop: C[128x256] = A[128xK] * B^T (B stored [N][K]), BK=64 ----
// Single-buffered; LDS contract (proven zero-conflict): element (row r,
// 8-group g) at halfword r*64 + (g^(r&7))*8. 4 waves as 2(m) x 2(n);
// wave tile 64x128 -> acc[4][8].
template<bool A_F32>
__device__ __forceinline__ void run_kloop_wide(const void* Arow0, const _Float16* Brow0,
                                               int lda, int ldb, int kIters,
                                               _Float16* As, _Float16* Bs,
                                               f32x4 (&acc)[4][8])
{
  const int tid  = threadIdx.x;
  const int lane = tid & 63;
  const int w    = tid >> 6;
  const int wm   = w >> 1, wn = w & 1;
  const int srow = tid >> 3;          // staging row within 32-row chunk
  const int sg   = tid & 7;           // staging 8-elem group slot
  const int swz  = sg ^ (srow & 7);   // swizzled group (source side)
  const int fr   = lane & 15;
  const int fq   = lane >> 4;
  const int fx   = lane & 7;

  for (int it = 0; it < kIters; ++it) {
    const int k0 = it * 64;
    if constexpr (A_F32) {
      const float* A = (const float*)Arow0;
      f32x4 preF[8];
      #pragma unroll
      for (int i = 0; i < 4; ++i) {
        const float* src = A + (size_t)(i*32 + srow) * lda + (k0 + sg*8);
        preF[2*i]   = *(const f32x4*)src;
        preF[2*i+1] = *(const f32x4*)(src + 4);
      }
      #pragma unroll
      for (int i = 0; i < 8; ++i)   // B: 256 rows
        gload16(Brow0 + (size_t)(i*32 + srow) * ldb + (k0 + swz*8), Bs + i*2048 + w*512);
      #pragma unroll
      for (int i = 0; i < 4; ++i) {
        f32x4 x = preF[2*i], y = preF[2*i+1];
        half8 h;
        h[0]=(_Float16)x[0]; h[1]=(_Float16)x[1]; h[2]=(_Float16)x[2]; h[3]=(_Float16)x[3];
        h[4]=(_Float16)y[0]; h[5]=(_Float16)y[1]; h[6]=(_Float16)y[2]; h[7]=(_Float16)y[3];
        *(half8*)(As + (i*32 + srow)*64 + swz*8) = h;
      }
    } else {
      const _Float16* A = (const _Float16*)Arow0;
      #pragma unroll
      for (int i = 0; i < 4; ++i)
        gload16(A + (size_t)(i*32 + srow) * lda + (k0 + swz*8), As + i*2048 + w*512);
      #pragma unroll
      for (int i = 0; i < 8; ++i)
        gload16(Brow0 + (size_t)(i*32 + srow) * ldb + (k0 + swz*8), Bs + i*2048 + w*512);
    }
    __syncthreads();

    #pragma unroll
    for (int ks = 0; ks < 2; ++ks) {
      half8 av[4], bv[8];
      const int slot = (ks*4 + fq) ^ fx;
      #pragma unroll
      for (int i = 0; i < 4; ++i)
        av[i] = *(const half8*)(As + (wm*64 + i*16 + fr)*64 + slot*8);
      #pragma unroll
      for (int j = 0; j < 8; ++j)
        bv[j] = *(const half8*)(Bs + (wn*128 + j*16 + fr)*64 + slot*8);
      #pragma unroll
      for (int i = 0; i < 4; ++i) {
        #pragma unroll
        for (int j = 0; j < 8; ++j)
          acc[i][j] = __builtin_amdgcn_mfma_f32_16x16x32_f16(av[i], bv[j], acc[i][j], 0, 0, 0);
      }
    }
    __syncthreads();
  }
}

// ---- narrow K-loop (pv): C[128x128], BK=64, single-buffered (R9 exact) ----
__device__ __forceinline__ void run_kloop_sb(const _Float16* Arow0, const _Float16* Brow0,
                                             int lda, int ldb, int kIters,
                                             _Float16* As, _Float16* Bs,
                                             f32x4 (&acc)[4][4])
{
  const int tid  = threadIdx.x;
  const int lane = tid & 63;
  const int w    = tid >> 6;
  const int wm   = w >> 1, wn = w & 1;
  const int srow = tid >> 3;
  const int sg   = tid & 7;
  const int swz  = sg ^ (srow & 7);
  const int fr   = lane & 15;
  const int fq   = lane >> 4;
  const int fx   = lane & 7;

  for (int it = 0; it < kIters; ++it) {
    const int k0 = it * 64;
    #pragma unroll
    for (int i = 0; i < 4; ++i)
      gload16(Arow0 + (size_t)(i*32 + srow) * lda + (k0 + swz*8), As + i*2048 + w*512);
    #pragma unroll
    for (int i = 0; i < 4; ++i)
      gload16(Brow0 + (size_t)(i*32 + srow) * ldb + (k0 + swz*8), Bs + i*2048 + w*512);
    __syncthreads();

    #pragma unroll
    for (int ks = 0; ks < 2; ++ks) {
      half8 av[4], bv[4];
      const int slot = (ks*4 + fq) ^ fx;
      #pragma unroll
      for (int i = 0; i < 4; ++i) {
        av[i] = *(const half8*)(As + (wm*64 + i*16 + fr)*64 + slot*8);
        bv[i] = *(const half8*)(Bs + (wn*64 + i*16 + fr)*64 + slot*8);
      }
      #pragma unroll
      for (int i = 0; i < 4; ++i) {
        #pragma unroll
        for (int j = 0; j < 4; ++j)
          acc[i][j] = __builtin_amdgcn_mfma_f32_16x16x32_f16(av[i], bv[j], acc[i][j], 0, 0, 0);
      }
    }
    __syncthreads();
  }
}

// ---- weights fp32 -> f16 (3 x 512x512 concatenated) ----
__global__ __launch_bounds__(256) void k_cvtw(const float* __restrict__ Wq,
                                              const float* __restrict__ Wk,
                                              const float* __restrict__ Wv,
                                              _Float16* __restrict__ Wb)
{
  const int t = blockIdx.x * 256 + threadIdx.x;
  const int base = t * 8;
  const int z = base >> 18;
  const int off = base & 262143;
  const float* src = (z == 0) ? Wq : ((z == 1) ? Wk : Wv);
  f32x4 a = *(const f32x4*)(src + off);
  f32x4 b = *(const f32x4*)(src + off + 4);
  half8 h;
  h[0]=(_Float16)a[0]; h[1]=(_Float16)a[1]; h[2]=(_Float16)a[2]; h[3]=(_Float16)a[3];
  h[4]=(_Float16)b[0]; h[5]=(_Float16)b[1]; h[6]=(_Float16)b[2]; h[7]=(_Float16)b[3];
  *(half8*)(Wb + base) = h;
}

// ---- projections: X[16384x512](fp32) @ W^T + bias -> f16; V direct-transposed ----
// 1D grid 768: xcd = bid%8; i = bid/8 (0..95); p = xcd*48 + i/2; nt2 = i%2;
// z = p/128, mt = p%128. Block output 128 x 256 (cols nt2*256..+256).
__global__ __launch_bounds__(256, 2) void k_proj(const float* __restrict__ q,
                                                 const float* __restrict__ k,
                                                 const float* __restrict__ v,
                                                 const _Float16* __restrict__ Wb,
                                                 const float* __restrict__ bq,
                                                 const float* __restrict__ bk,
                                                 const float* __restrict__ bv,
                                                 _Float16* __restrict__ Qb,
                                                 _Float16* __restrict__ Kb,
                                                 _Float16* __restrict__ Vt)
{
  // union: {As 8192 + Bs 16384 halfs = 48KB} / V-transpose tile [256][132] = 66KB
  __shared__ __align__(16) _Float16 LDSbuf[256*132];
  _Float16* As = LDSbuf;
  _Float16* Bs = LDSbuf + 8192;

  const int bid = blockIdx.x;
  const int xcd = bid & 7, i = bid >> 3;
  const int p = xcd * 48 + (i >> 1);
  const int nt2 = i & 1;
  const int z = p >> 7, mt = p & 127;

  const float* A     = (z == 0) ? q  : (z == 1) ? k  : v;
  const float* bia   = (z == 0) ? bq : (z == 1) ? bk : bv;
  const _Float16* B  = Wb + (size_t)z * 512 * 512;

  f32x4 acc[4][8] = {};
  run_kloop_wide<true>(A + (size_t)mt*128*512, B + (size_t)nt2*256*512, 512, 512, 8,
                       As, Bs, acc);

  const int tid = threadIdx.x;
  const int lane = tid & 63, w = tid >> 6;
  const int wm = w >> 1, wn = w & 1;
  const int fr = lane & 15, fq = lane >> 4;   // C/D: col=lane&15, row=(lane>>4)*4+reg

  if (z < 2) {
    _Float16* C = (z == 0) ? Qb : Kb;
    #pragma unroll
    for (int j = 0; j < 8; ++j) {
      const int col = nt2*256 + wn*128 + j*16 + fr;
      const float bval = bia[col];
      #pragma unroll
      for (int i2 = 0; i2 < 4; ++i2) {
        const int row = mt*128 + wm*64 + i2*16 + fq*4;
        #pragma unroll
        for (int r = 0; r < 4; ++r)
          C[(size_t)(row + r) * 512 + col] = (_Float16)(acc[i2][j][r] + bval);
      }
    }
  } else {
    // V: stage transposed tile in LDS [col 256][row 128 + pad 4], write Vt coalesced.
    _Float16* sm = LDSbuf;   // kloop ended with syncthreads: LDS free
    #pragma unroll
    for (int j = 0; j < 8; ++j) {
      const int colloc = wn*128 + j*16 + fr;          // 0..255 (d within block)
      const float bval = bia[nt2*256 + colloc];
      #pragma unroll
      for (int i2 = 0; i2 < 4; ++i2) {
        const int rowloc = wm*64 + i2*16 + fq*4;      // 0..127 (s within tile)
        #pragma unroll
        for (int r = 0; r < 4; ++r)
          sm[colloc*132 + rowloc + r] = (_Float16)(acc[i2][j][r] + bval);
      }
    }
    __syncthreads();
    const int bb = mt >> 4, s0 = (mt & 15) * 128;
    #pragma unroll
    for (int q8 = 0; q8 < 16; ++q8) {
      const int dloc = q8*16 + (tid >> 4);            // 0..255
      const int ch   = tid & 15;
      half8 o = *(const half8*)&sm[dloc*132 + ch*8];
      *(half8*)(Vt + ((size_t)bb*512 + nt2*256 + dloc)*2048 + s0 + ch*8) = o;
    }
  }
}

// ---- scores: S = Q K^T * scale, kt-PAIRS (128x256 per block) ----
// grid 576: b = bid%8 (-> XCD b); t = 71 - bid/8 (heavy-first) decoded to
// (qt, kt2); kt0 = 2*kt2 <= qt (even). Sub-tile kt = kt0 + wn; store only
// kt<=qt; diagonal sub-tile masked with -30000 (softmax exp -> 0).
__global__ __launch_bounds__(256, 2) void k_scores(const _Float16* __restrict__ Qb,
                                                   const _Float16* __restrict__ Kb,
                                                   _Float16* __restrict__ P)
{
  __shared__ __align__(16) _Float16 As[128*64], Bs[256*64];   // 48 KB
  const int bid = blockIdx.x;
  const int b = bid & 7;
  const int t = 71 - (bid >> 3);
  int qt = 0, accum = 0;
  while (accum + (qt >> 1) + 1 <= t) { accum += (qt >> 1) + 1; ++qt; }
  const int kt0 = (t - accum) * 2;

  f32x4 acc[4][8] = {};
  run_kloop_wide<false>(Qb + ((size_t)b*2048 + qt*128)*512,
                        Kb + ((size_t)b*2048 + kt0*128)*512,
                        512, 512, 8, As, Bs, acc);

  const int lane = threadIdx.x & 63, w = threadIdx.x >> 6;
  const int wm = w >> 1, wn = w & 1;
  const int fr = lane & 15, fq = lane >> 4;

  const int kt = kt0 + wn;
  if (kt <= qt) {
    const bool diag = (kt == qt);
    #pragma unroll
    for (int i = 0; i < 4; ++i) {
      const int rl = wm*64 + i*16 + fq*4;
      #pragma unroll
      for (int j = 0; j < 8; ++j) {
        const int cl = j*16 + fr;                     // col within sub-tile
        #pragma unroll
        for (int r = 0; r < 4; ++r) {
          const float sc = acc[i][j][r] * SCALE_QK;
          const bool msk = diag && (cl > rl + r);
          P[((size_t)b*2048 + qt*128 + rl + r) * 2048 + kt*128 + cl] =
              msk ? (_Float16)(-30000.0f) : (_Float16)sc;
        }
      }
    }
  }
}

// ---- in-place causal row softmax; one wave per row; row cached in regs ----
__global__ __launch_bounds__(256) void k_softmax(_Float16* __restrict__ P)
{
  const int lane = threadIdx.x & 63;
  const int row  = blockIdx.x * 4 + (threadIdx.x >> 6);  // 0..16383 (= b*2048+q)
  const int qIdx = row & 2047;
  _Float16* p = P + (size_t)row * 2048;
  const int L    = qIdx + 1;
  const int Lpad = ((qIdx >> 7) + 1) * 128;     // PV kernel reads up to here

  half8 xb[4];
  float m = -1e30f, s = 0.f;
  #pragma unroll
  for (int c = 0; c < 4; ++c) {
    const int i0 = lane * 8 + c * 512;
    if (i0 < Lpad) {
      half8 x = *(const half8*)(p + i0);
      xb[c] = x;
      float xv[8];
      #pragma unroll
      for (int j = 0; j < 8; ++j) xv[j] = (i0 + j < L) ? (float)x[j] : -1e30f;
      float cm = xv[0];
      #pragma unroll
      for (int j = 1; j < 8; ++j) cm = fmaxf(cm, xv[j]);
      const float mn = fmaxf(m, cm);
      float cs = 0.f;
      #pragma unroll
      for (int j = 0; j < 8; ++j) cs += __expf(xv[j] - mn);
      s = s * __expf(m - mn) + cs;
      m = mn;
    }
  }
  #pragma unroll
  for (int d = 1; d < 64; d <<= 1) {
    const float mo = __shfl_xor(m, d, 64);
    const float so = __shfl_xor(s, d, 64);
    const float mn = fmaxf(m, mo);
    s = s * __expf(m - mn) + so * __expf(mo - mn);
    m = mn;
  }
  const float inv = 1.0f / s;

  #pragma unroll
  for (int c = 0; c < 4; ++c) {
    const int i0 = lane * 8 + c * 512;
    if (i0 < Lpad) {
      half8 x = xb[c];
      half8 o;
      #pragma unroll
      for (int j = 0; j < 8; ++j)
        o[j] = (i0 + j < L) ? (_Float16)(__expf((float)x[j] - m) * inv) : (_Float16)0.f;
      *(half8*)(p + i0) = o;
    }
  }
}

// ---- out = P @ V  (B-operand = Vt[d][s]), causal K-extent ----
// 1D grid 512: b = bid%8 (-> XCD b); r = bid/8 in [0,64): qi=r/4 interleaved
// long/short (phase-balanced block pairs per CU), dt=r%4 (P rows L2-hot).
__global__ __launch_bounds__(256, 4) void k_pv(const _Float16* __restrict__ P,
                                               const _Float16* __restrict__ Vt,
                                               float* __restrict__ Out)
{
  __shared__ __align__(16) _Float16 As[128*64], Bs[128*64];   // 32 KB
  const int bid = blockIdx.x;
  const int b = bid & 7;
  const int r0 = bid >> 3;
  const int qi = r0 >> 2, dt = r0 & 3;
  const int qt = (qi & 1) ? (15 - (qi >> 1)) : (qi >> 1);

  f32x4 acc[4][4] = {};
  run_kloop_sb(P  + ((size_t)b*2048 + qt*128)*2048,
               Vt + ((size_t)b*512  + dt*128)*2048,
               2048, 2048, (qt + 1) * 2, As, Bs, acc);
  const int lane = threadIdx.x & 63, w = threadIdx.x >> 6;
  const int wm = w >> 1, wn = w & 1;
  const int fr = lane & 15, fq = lane >> 4;
  #pragma unroll
  for (int i = 0; i < 4; ++i) {
    const int row = qt*128 + wm*64 + i*16 + fq*4;
    #pragma unroll
    for (int j = 0; j < 4; ++j) {
      const int col = dt*128 + wn*64 + j*16 + fr;
      #pragma unroll
      for (int r = 0; r < 4; ++r)
        Out[((size_t)b*2048 + row + r) * 512 + col] = acc[i][j][r];
    }
  }
}

extern "C" void kernel_launch(void* const* d_in, const int* in_sizes, int n_in,
                              void* d_out, int out_size, void* d_ws, size_t ws_size,
                              hipStream_t stream) {
  (void)in_sizes; (void)n_in; (void)out_size;
  const float* q  = (const float*)d_in[0];
  const float* k  = (const float*)d_in[1];
  const float* v  = (const float*)d_in[2];
  // d_in[3] = causal mask: always tril per setup; implemented structurally.
  const float* Wq = (const float*)d_in[4];
  const float* bq = (const float*)d_in[5];
  const float* Wk = (const float*)d_in[6];
  const float* bk = (const float*)d_in[7];
  const float* Wv = (const float*)d_in[8];
  const float* bv = (const float*)d_in[9];

  const size_t OFF_P  = 0;
  const size_t OFF_Q  = (size_t)64 << 20;
  const size_t OFF_K  = (size_t)80 << 20;
  const size_t OFF_VT = (size_t)112 << 20;
  const size_t OFF_W  = (size_t)128 << 20;
  const size_t NEEDED = OFF_W + (size_t)3 * 512 * 512 * sizeof(_Float16);
  if (ws_size < NEEDED) return;  // diagnostic: poison-level absmax => ws too small

  char* ws = (char*)d_ws;
  _Float16* P  = (_Float16*)(ws + OFF_P);
  _Float16* Qb = (_Float16*)(ws + OFF_Q);
  _Float16* Kb = (_Float16*)(ws + OFF_K);
  _Float16* Vt = (_Float16*)(ws + OFF_VT);
  _Float16* Wb = (_Float16*)(ws + OFF_W);
  float* Out = (float*)d_out;

  k_cvtw   <<<dim3(384),  dim3(256), 0, stream>>>(Wq, Wk, Wv, Wb);
  k_proj   <<<dim3(768),  dim3(256), 0, stream>>>(q, k, v, Wb, bq, bk, bv, Qb, Kb, Vt);
  k_scores <<<dim3(576),  dim3(256), 0, stream>>>(Qb, Kb, P);
  k_softmax<<<dim3(4096), dim3(256), 0, stream>>>(P);
  k_pv     <<<dim3(512),  dim3(256), 0, stream>>>(P, Vt, Out);
}

// Round 9
// 266.778 us; speedup vs baseline: 1.0181x; 1.0140x over previous
//
// AttentionModel: fused QKV projection + causal softmax attention, MI355X/gfx950.
// Round 12: composite of measured per-kernel winners. Consolidated law
// (R4-R11): time ~ staged-bytes/6TB/s with a sharp penalty below ~3 blocks/CU;
// sync scheme / phase size / prefetch depth are all second-order; VGPR
// (acc[4][4]=64) caps occupancy at 4 waves/SIMD.
//  - proj  = R11 (64.5us measured): nt2-PAIRS 128x256, A fp32 re-read 2x not
//    4x, 2 blocks/CU unchanged, V written direct-transposed ([256][132] LDS
//    union). + NEW: Qb (and bq) pre-scaled by 1/sqrt(512) at the epilogue.
//  - scores = R9 (1088 triangular blocks, (256,4), 32KB): R11's kt-pair
//    variant halved blocks/CU and cost +12us -- reverted. Epilogue drops the
//    SCALE_QK multiply (Q pre-scaled).
//  - pv / softmax / cvtw = R9 exact (best total 262.7).
// ws layout (bytes): P 0..64M | Qb 64M | Kb 80M | Vt 112M | Wf16 128M

#include <hip/hip_runtime.h>
#include <stdint.h>
#include <stddef.h>
#include <math.h>

typedef _Float16 half8 __attribute__((ext_vector_type(8)));
typedef float f32x4 __attribute__((ext_vector_type(4)));

#define SCALE_QK 0.04419417382415922f  // 1/sqrt(512)

__device__ __forceinline__ void gload16(const void* g, void* lds) {
  __builtin_amdgcn_global_load_lds(
      (const __attribute__((address_space(1))) void*)g,
      (__attribute__((address_space(3))) void*)lds,
      16, 0, 0);
}

// ---- wide K-loop: C[128x256] = A[128xK](fp32) * B^T, BK=64, single-buffered.
// LDS contract (proven zero-conflict): element (row r, 8-group g) at halfword
// r*64 + (g^(r&7))*8. 4 waves as 2(m) x 2(n); wave tile 64x128 -> acc[4][8].
__device__ __forceinline__ void run_kloop_wide(const float* Arow0, const _Float16* Brow0,
                                               int lda, int ldb, int kIters,
                                               _Float16* As, _Float16* Bs,
                                               f32x4 (&acc)[4][8])
{
  const int tid  = threadIdx.x;
  const int lane = tid & 63;
  const int w    = tid >> 6;
  const int wm   = w >> 1, wn = w & 1;
  const int srow = tid >> 3;          // staging row within 32-row chunk
  const int sg   = tid & 7;           // staging 8-elem group slot
  const int swz  = sg ^ (srow & 7);   // swizzled group (source side)
  const int fr   = lane & 15;
  const int fq   = lane >> 4;
  const int fx   = lane & 7;

  for (int it = 0; it < kIters; ++it) {
    const int k0 = it * 64;
    f32x4 preF[8];
    #pragma unroll
    for (int i = 0; i < 4; ++i) {
      const float* src = Arow0 + (size_t)(i*32 + srow) * lda + (k0 + sg*8);
      preF[2*i]   = *(const f32x4*)src;
      preF[2*i+1] = *(const f32x4*)(src + 4);
    }
    #pragma unroll
    for (int i = 0; i < 8; ++i)   // B: 256 rows
      gload16(Brow0 + (size_t)(i*32 + srow) * ldb + (k0 + swz*8), Bs + i*2048 + w*512);
    #pragma unroll
    for (int i = 0; i < 4; ++i) {
      f32x4 x = preF[2*i], y = preF[2*i+1];
      half8 h;
      h[0]=(_Float16)x[0]; h[1]=(_Float16)x[1]; h[2]=(_Float16)x[2]; h[3]=(_Float16)x[3];
      h[4]=(_Float16)y[0]; h[5]=(_Float16)y[1]; h[6]=(_Float16)y[2]; h[7]=(_Float16)y[3];
      *(half8*)(As + (i*32 + srow)*64 + swz*8) = h;
    }
    __syncthreads();

    #pragma unroll
    for (int ks = 0; ks < 2; ++ks) {
      half8 av[4], bv[8];
      const int slot = (ks*4 + fq) ^ fx;
      #pragma unroll
      for (int i = 0; i < 4; ++i)
        av[i] = *(const half8*)(As + (wm*64 + i*16 + fr)*64 + slot*8);
      #pragma unroll
      for (int j = 0; j < 8; ++j)
        bv[j] = *(const half8*)(Bs + (wn*128 + j*16 + fr)*64 + slot*8);
      #pragma unroll
      for (int i = 0; i < 4; ++i) {
        #pragma unroll
        for (int j = 0; j < 8; ++j)
          acc[i][j] = __builtin_amdgcn_mfma_f32_16x16x32_f16(av[i], bv[j], acc[i][j], 0, 0, 0);
      }
    }
    __syncthreads();
  }
}

// ---- narrow K-loop: C[128x128], BK=64, single-buffered (R9 exact) ----
__device__ __forceinline__ void run_kloop_sb(const _Float16* Arow0, const _Float16* Brow0,
                                             int lda, int ldb, int kIters,
                                             _Float16* As, _Float16* Bs,
                                             f32x4 (&acc)[4][4])
{
  const int tid  = threadIdx.x;
  const int lane = tid & 63;
  const int w    = tid >> 6;
  const int wm   = w >> 1, wn = w & 1;
  const int srow = tid >> 3;
  const int sg   = tid & 7;
  const int swz  = sg ^ (srow & 7);
  const int fr   = lane & 15;
  const int fq   = lane >> 4;
  const int fx   = lane & 7;

  for (int it = 0; it < kIters; ++it) {
    const int k0 = it * 64;
    #pragma unroll
    for (int i = 0; i < 4; ++i)
      gload16(Arow0 + (size_t)(i*32 + srow) * lda + (k0 + swz*8), As + i*2048 + w*512);
    #pragma unroll
    for (int i = 0; i < 4; ++i)
      gload16(Brow0 + (size_t)(i*32 + srow) * ldb + (k0 + swz*8), Bs + i*2048 + w*512);
    __syncthreads();

    #pragma unroll
    for (int ks = 0; ks < 2; ++ks) {
      half8 av[4], bv[4];
      const int slot = (ks*4 + fq) ^ fx;
      #pragma unroll
      for (int i = 0; i < 4; ++i) {
        av[i] = *(const half8*)(As + (wm*64 + i*16 + fr)*64 + slot*8);
        bv[i] = *(const half8*)(Bs + (wn*64 + i*16 + fr)*64 + slot*8);
      }
      #pragma unroll
      for (int i = 0; i < 4; ++i) {
        #pragma unroll
        for (int j = 0; j < 4; ++j)
          acc[i][j] = __builtin_amdgcn_mfma_f32_16x16x32_f16(av[i], bv[j], acc[i][j], 0, 0, 0);
      }
    }
    __syncthreads();
  }
}

// ---- weights fp32 -> f16 (3 x 512x512 concatenated) ----
__global__ __launch_bounds__(256) void k_cvtw(const float* __restrict__ Wq,
                                              const float* __restrict__ Wk,
                                              const float* __restrict__ Wv,
                                              _Float16* __restrict__ Wb)
{
  const int t = blockIdx.x * 256 + threadIdx.x;
  const int base = t * 8;
  const int z = base >> 18;
  const int off = base & 262143;
  const float* src = (z == 0) ? Wq : ((z == 1) ? Wk : Wv);
  f32x4 a = *(const f32x4*)(src + off);
  f32x4 b = *(const f32x4*)(src + off + 4);
  half8 h;
  h[0]=(_Float16)a[0]; h[1]=(_Float16)a[1]; h[2]=(_Float16)a[2]; h[3]=(_Float16)a[3];
  h[4]=(_Float16)b[0]; h[5]=(_Float16)b[1]; h[6]=(_Float16)b[2]; h[7]=(_Float16)b[3];
  *(half8*)(Wb + base) = h;
}

// ---- projections: X[16384x512](fp32) @ W^T + bias -> f16; V direct-transposed ----
// 1D grid 768: xcd = bid%8; i = bid/8 (0..95); p = xcd*48 + i/2; nt2 = i%2;
// z = p/128, mt = p%128. Block output 128 x 256 (cols nt2*256..+256).
// Q output (z==0) is PRE-SCALED by 1/sqrt(512) (bias included).
__global__ __launch_bounds__(256, 2) void k_proj(const float* __restrict__ q,
                                                 const float* __restrict__ k,
                                                 const float* __restrict__ v,
                                                 const _Float16* __restrict__ Wb,
                                                 const float* __restrict__ bq,
                                                 const float* __restrict__ bk,
                                                 const float* __restrict__ bv,
                                                 _Float16* __restrict__ Qb,
                                                 _Float16* __restrict__ Kb,
                                                 _Float16* __restrict__ Vt)
{
  // union: {As 8192 + Bs 16384 halfs = 48KB} / V-transpose tile [256][132] = 66KB
  __shared__ __align__(16) _Float16 LDSbuf[256*132];
  _Float16* As = LDSbuf;
  _Float16* Bs = LDSbuf + 8192;

  const int bid = blockIdx.x;
  const int xcd = bid & 7, i = bid >> 3;
  const int p = xcd * 48 + (i >> 1);
  const int nt2 = i & 1;
  const int z = p >> 7, mt = p & 127;

  const float* A     = (z == 0) ? q  : (z == 1) ? k  : v;
  const float* bia   = (z == 0) ? bq : (z == 1) ? bk : bv;
  const _Float16* B  = Wb + (size_t)z * 512 * 512;

  f32x4 acc[4][8] = {};
  run_kloop_wide(A + (size_t)mt*128*512, B + (size_t)nt2*256*512, 512, 512, 8,
                 As, Bs, acc);

  const int tid = threadIdx.x;
  const int lane = tid & 63, w = tid >> 6;
  const int wm = w >> 1, wn = w & 1;
  const int fr = lane & 15, fq = lane >> 4;   // C/D: col=lane&15, row=(lane>>4)*4+reg

  if (z < 2) {
    _Float16* C = (z == 0) ? Qb : Kb;
    const float osc = (z == 0) ? SCALE_QK : 1.0f;   // pre-scale Q (and its bias)
    #pragma unroll
    for (int j = 0; j < 8; ++j) {
      const int col = nt2*256 + wn*128 + j*16 + fr;
      const float bval = bia[col];
      #pragma unroll
      for (int i2 = 0; i2 < 4; ++i2) {
        const int row = mt*128 + wm*64 + i2*16 + fq*4;
        #pragma unroll
        for (int r = 0; r < 4; ++r)
          C[(size_t)(row + r) * 512 + col] = (_Float16)((acc[i2][j][r] + bval) * osc);
      }
    }
  } else {
    // V: stage transposed tile in LDS [col 256][row 128 + pad 4], write Vt coalesced.
    _Float16* sm = LDSbuf;   // kloop ended with syncthreads: LDS free
    #pragma unroll
    for (int j = 0; j < 8; ++j) {
      const int colloc = wn*128 + j*16 + fr;          // 0..255 (d within block)
      const float bval = bia[nt2*256 + colloc];
      #pragma unroll
      for (int i2 = 0; i2 < 4; ++i2) {
        const int rowloc = wm*64 + i2*16 + fq*4;      // 0..127 (s within tile)
        #pragma unroll
        for (int r = 0; r < 4; ++r)
          sm[colloc*132 + rowloc + r] = (_Float16)(acc[i2][j][r] + bval);
      }
    }
    __syncthreads();
    const int bb = mt >> 4, s0 = (mt & 15) * 128;
    #pragma unroll
    for (int q8 = 0; q8 < 16; ++q8) {
      const int dloc = q8*16 + (tid >> 4);            // 0..255
      const int ch   = tid & 15;
      half8 o = *(const half8*)&sm[dloc*132 + ch*8];
      *(half8*)(Vt + ((size_t)bb*512 + nt2*256 + dloc)*2048 + s0 + ch*8) = o;
    }
  }
}

// ---- scores: S = (Q*scale) K^T  (Q pre-scaled at proj) ----
// 1D grid 1088: b = bid%8 (-> XCD b); t = bid/8 triangular-decoded to (qt,kt),
// kt<=qt. Per-batch Q+K (4MB) is L2-resident on its XCD.
__global__ __launch_bounds__(256, 4) void k_scores(const _Float16* __restrict__ Qb,
                                                   const _Float16* __restrict__ Kb,
                                                   _Float16* __restrict__ P)
{
  __shared__ __align__(16) _Float16 As[128*64], Bs[128*64];   // 32 KB
  const int bid = blockIdx.x;
  const int b = bid & 7;
  const int t = bid >> 3;
  int qt = (int)((sqrtf(8.0f * (float)t + 1.0f) - 1.0f) * 0.5f);
  int base = (qt * (qt + 1)) >> 1;
  if (t < base)                { --qt; base = (qt * (qt + 1)) >> 1; }
  else if (t >= base + qt + 1) { ++qt; base = (qt * (qt + 1)) >> 1; }
  const int kt = t - base;

  f32x4 acc[4][4] = {};
  run_kloop_sb(Qb + ((size_t)b*2048 + qt*128)*512,
               Kb + ((size_t)b*2048 + kt*128)*512,
               512, 512, 8, As, Bs, acc);
  const int lane = threadIdx.x & 63, w = threadIdx.x >> 6;
  const int wm = w >> 1, wn = w & 1;
  const int fr = lane & 15, fq = lane >> 4;
  #pragma unroll
  for (int i = 0; i < 4; ++i) {
    const int row = qt*128 + wm*64 + i*16 + fq*4;
    #pragma unroll
    for (int j = 0; j < 4; ++j) {
      const int col = kt*128 + wn*64 + j*16 + fr;
      #pragma unroll
      for (int r = 0; r < 4; ++r)
        P[((size_t)b*2048 + row + r) * 2048 + col] = (_Float16)acc[i][j][r];
    }
  }
}

// ---- in-place causal row softmax; one wave per row; row cached in regs ----
__global__ __launch_bounds__(256) void k_softmax(_Float16* __restrict__ P)
{
  const int lane = threadIdx.x & 63;
  const int row  = blockIdx.x * 4 + (threadIdx.x >> 6);  // 0..16383 (= b*2048+q)
  const int qIdx = row & 2047;
  _Float16* p = P + (size_t)row * 2048;
  const int L    = qIdx + 1;
  const int Lpad = ((qIdx >> 7) + 1) * 128;     // PV kernel reads up to here

  half8 xb[4];
  float m = -1e30f, s = 0.f;
  #pragma unroll
  for (int c = 0; c < 4; ++c) {
    const int i0 = lane * 8 + c * 512;
    if (i0 < Lpad) {
      half8 x = *(const half8*)(p + i0);
      xb[c] = x;
      float xv[8];
      #pragma unroll
      for (int j = 0; j < 8; ++j) xv[j] = (i0 + j < L) ? (float)x[j] : -1e30f;
      float cm = xv[0];
      #pragma unroll
      for (int j = 1; j < 8; ++j) cm = fmaxf(cm, xv[j]);
      const float mn = fmaxf(m, cm);
      float cs = 0.f;
      #pragma unroll
      for (int j = 0; j < 8; ++j) cs += __expf(xv[j] - mn);
      s = s * __expf(m - mn) + cs;
      m = mn;
    }
  }
  #pragma unroll
  for (int d = 1; d < 64; d <<= 1) {
    const float mo = __shfl_xor(m, d, 64);
    const float so = __shfl_xor(s, d, 64);
    const float mn = fmaxf(m, mo);
    s = s * __expf(m - mn) + so * __expf(mo - mn);
    m = mn;
  }
  const float inv = 1.0f / s;

  #pragma unroll
  for (int c = 0; c < 4; ++c) {
    const int i0 = lane * 8 + c * 512;
    if (i0 < Lpad) {
      half8 x = xb[c];
      half8 o;
      #pragma unroll
      for (int j = 0; j < 8; ++j)
        o[j] = (i0 + j < L) ? (_Float16)(__expf((float)x[j] - m) * inv) : (_Float16)0.f;
      *(half8*)(p + i0) = o;
    }
  }
}

// ---- out = P @ V  (B-operand = Vt[d][s]), causal K-extent ----
// 1D grid 512: b = bid%8 (-> XCD b); r = bid/8 in [0,64): qi=r/4 interleaved
// long/short (phase-balanced block pairs per CU), dt=r%4 (P rows L2-hot).
__global__ __launch_bounds__(256, 4) void k_pv(const _Float16* __restrict__ P,
                                               const _Float16* __restrict__ Vt,
                                               float* __restrict__ Out)
{
  __shared__ __align__(16) _Float16 As[128*64], Bs[128*64];   // 32 KB
  const int bid = blockIdx.x;
  const int b = bid & 7;
  const int r0 = bid >> 3;
  const int qi = r0 >> 2, dt = r0 & 3;
  const int qt = (qi & 1) ? (15 - (qi >> 1)) : (qi >> 1);

  f32x4 acc[4][4] = {};
  run_kloop_sb(P  + ((size_t)b*2048 + qt*128)*2048,
               Vt + ((size_t)b*512  + dt*128)*2048,
               2048, 2048, (qt + 1) * 2, As, Bs, acc);
  const int lane = threadIdx.x & 63, w = threadIdx.x >> 6;
  const int wm = w >> 1, wn = w & 1;
  const int fr = lane & 15, fq = lane >> 4;
  #pragma unroll
  for (int i = 0; i < 4; ++i) {
    const int row = qt*128 + wm*64 + i*16 + fq*4;
    #pragma unroll
    for (int j = 0; j < 4; ++j) {
      const int col = dt*128 + wn*64 + j*16 + fr;
      #pragma unroll
      for (int r = 0; r < 4; ++r)
        Out[((size_t)b*2048 + row + r) * 512 + col] = acc[i][j][r];
    }
  }
}

extern "C" void kernel_launch(void* const* d_in, const int* in_sizes, int n_in,
                              void* d_out, int out_size, void* d_ws, size_t ws_size,
                              hipStream_t stream) {
  (void)in_sizes; (void)n_in; (void)out_size;
  const float* q  = (const float*)d_in[0];
  const float* k  = (const float*)d_in[1];
  const float* v  = (const float*)d_in[2];
  // d_in[3] = causal mask: always tril per setup; implemented structurally.
  const float* Wq = (const float*)d_in[4];
  const float* bq = (const float*)d_in[5];
  const float* Wk = (const float*)d_in[6];
  const float* bk = (const float*)d_in[7];
  const float* Wv = (const float*)d_in[8];
  const float* bv = (const float*)d_in[9];

  const size_t OFF_P  = 0;
  const size_t OFF_Q  = (size_t)64 << 20;
  const size_t OFF_K  = (size_t)80 << 20;
  const size_t OFF_VT = (size_t)112 << 20;
  const size_t OFF_W  = (size_t)128 << 20;
  const size_t NEEDED = OFF_W + (size_t)3 * 512 * 512 * sizeof(_Float16);
  if (ws_size < NEEDED) return;  // diagnostic: poison-level absmax => ws too small

  char* ws = (char*)d_ws;
  _Float16* P  = (_Float16*)(ws + OFF_P);
  _Float16* Qb = (_Float16*)(ws + OFF_Q);
  _Float16* Kb = (_Float16*)(ws + OFF_K);
  _Float16* Vt = (_Float16*)(ws + OFF_VT);
  _Float16* Wb = (_Float16*)(ws + OFF_W);
  float* Out = (float*)d_out;

  k_cvtw   <<<dim3(384),  dim3(256), 0, stream>>>(Wq, Wk, Wv, Wb);
  k_proj   <<<dim3(768),  dim3(256), 0, stream>>>(q, k, v, Wb, bq, bk, bv, Qb, Kb, Vt);
  k_scores <<<dim3(1088), dim3(256), 0, stream>>>(Qb, Kb, P);
  k_softmax<<<dim3(4096), dim3(256), 0, stream>>>(P);
  k_pv     <<<dim3(512),  dim3(256), 0, stream>>>(P, Vt, Out);
}